// Round 4
// baseline (386.183 us; speedup 1.0000x reference)
//
#include <hip/hip_runtime.h>

// RNN scan: h_{t+1} = relu(W_hh @ h_t + x_t * w_x), out = W_hy @ h_T
// B=8192, T=512, H=64.
// In-order wave => wallclock = 512 x per-step critical path. Round 4:
//   - TWO independent 32-col batch chains per wave (grid 128): chain B's
//     issue fills chain A's MFMA/hazard stalls (classic ILP interleave).
//   - x-term via 5th MFMA (w_x,x in hi/lo bf16, 3 k-slices: wh*xh+wh*xl+wl*xh,
//     residual ~2^-18): removes per-slot wx vectors + 16 pk_muls; off-path.
//   - depth-4 single-acc k-chains (C-in = X): fewer live vectors, no pk_adds.
// Layouts (verified rounds 1-3):
//   A 32x32x16: row=lane&31, k=8*(lane>>5)+e
//   B: col=lane&31, k=8*(lane>>5)+e
//   C: col=lane&31, row=(reg&3)+8*(reg>>2)+4*(lane>>5)
//   permlane32_swap(X,Y): X'={self X|partner Y}, Y'={partner X|self Y}

typedef __bf16 bf16x8 __attribute__((ext_vector_type(8)));
typedef float f32x16 __attribute__((ext_vector_type(16)));
typedef unsigned int u32x4 __attribute__((ext_vector_type(4)));

#define RNN_B 8192
#define RNN_T 512
#define RNN_H 64

__device__ __forceinline__ unsigned pk2_relu(float a, float b) {
  float ra = fmaxf(a, 0.0f), rb = fmaxf(b, 0.0f);
  unsigned short ua = __builtin_bit_cast(unsigned short, (__bf16)ra);
  unsigned short ub = __builtin_bit_cast(unsigned short, (__bf16)rb);
  return (unsigned)ua | ((unsigned)ub << 16);
}

__device__ __forceinline__ void make_bx(float xv, int sel, unsigned& w0, unsigned& w1) {
  __bf16 xh = (__bf16)xv;
  __bf16 xl = (__bf16)(xv - (float)xh);
  unsigned uh = (unsigned)__builtin_bit_cast(unsigned short, xh);
  unsigned ul = (unsigned)__builtin_bit_cast(unsigned short, xl);
  w0 = sel ? 0u : (uh | (ul << 16));   // k0=xh, k1=xl
  w1 = sel ? 0u : uh;                  // k2=xh
}

__global__ __launch_bounds__(64, 1) void rnn_scan_kernel(
    const float* __restrict__ x,
    const float* __restrict__ Wxh,
    const float* __restrict__ Whh,
    const float* __restrict__ Why,
    float* __restrict__ out)
{
  const int lane = threadIdx.x;
  const int col  = lane & 31;
  const int sel  = lane >> 5;
  const int b0   = blockIdx.x * 64;          // 2 chains x 32 cols

  // ---- W_hh fragments (shared by both chains) ----
  bf16x8 A[2][4];
#pragma unroll
  for (int tau = 0; tau < 2; ++tau) {
#pragma unroll
    for (int m = 0; m < 4; ++m) {
      const float* wp = Whh + (32 * tau + col) * RNN_H + 16 * m + 8 * sel;
      float4 w0 = *(const float4*)(wp);
      float4 w1 = *(const float4*)(wp + 4);
      bf16x8 f;
      f[0] = (__bf16)w0.x; f[1] = (__bf16)w0.y; f[2] = (__bf16)w0.z; f[3] = (__bf16)w0.w;
      f[4] = (__bf16)w1.x; f[5] = (__bf16)w1.y; f[6] = (__bf16)w1.z; f[7] = (__bf16)w1.w;
      A[tau][m] = f;
    }
  }

  // ---- w_x fragments: k0=wh, k1=wh, k2=wl (sel=0 lanes only) ----
  bf16x8 Ax[2];
#pragma unroll
  for (int tau = 0; tau < 2; ++tau) {
    float w = Wxh[32 * tau + col];
    __bf16 wh = (__bf16)w;
    __bf16 wl = (__bf16)(w - (float)wh);
    bf16x8 f = {};
    if (sel == 0) { f[0] = wh; f[1] = wh; f[2] = wl; }
    Ax[tau] = f;
  }

  const float* xrA = x + (size_t)(b0 + col) * RNN_T;
  const float* xrB = x + (size_t)(b0 + 32 + col) * RNN_T;
  float4 xa0 = *(const float4*)(xrA), xa1 = *(const float4*)(xrA + 4);
  float4 xb0 = *(const float4*)(xrB), xb1 = *(const float4*)(xrB + 4);

  f32x16 zf = {};
  f32x16 accA0 = zf, accA1 = zf, accB0 = zf, accB1 = zf;  // final pre-relu h
  unsigned bfA[4][4], bfB[4][4];
#pragma unroll
  for (int m = 0; m < 4; ++m)
#pragma unroll
    for (int r = 0; r < 4; ++r) { bfA[m][r] = 0u; bfB[m][r] = 0u; }

  // X for t=0 (x-term MFMA, pipelined one step ahead)
  f32x16 XA0, XA1, XB0, XB1;
  {
    unsigned wa0, wa1, wb0, wb1;
    make_bx(xa0.x, sel, wa0, wa1);
    make_bx(xb0.x, sel, wb0, wb1);
    u32x4 ua = {wa0, wa1, 0u, 0u}, ub = {wb0, wb1, 0u, 0u};
    bf16x8 BxA = __builtin_bit_cast(bf16x8, ua);
    bf16x8 BxB = __builtin_bit_cast(bf16x8, ub);
    XA0 = __builtin_amdgcn_mfma_f32_32x32x16_bf16(Ax[0], BxA, zf, 0, 0, 0);
    XA1 = __builtin_amdgcn_mfma_f32_32x32x16_bf16(Ax[1], BxA, zf, 0, 0, 0);
    XB0 = __builtin_amdgcn_mfma_f32_32x32x16_bf16(Ax[0], BxB, zf, 0, 0, 0);
    XB1 = __builtin_amdgcn_mfma_f32_32x32x16_bf16(Ax[1], BxB, zf, 0, 0, 0);
  }

  for (int tb = 0; tb < RNN_T; tb += 8) {
    const int tn = (tb + 8 < RNN_T) ? tb + 8 : tb;
    float4 na0 = *(const float4*)(xrA + tn), na1 = *(const float4*)(xrA + tn + 4);
    float4 nb0 = *(const float4*)(xrB + tn), nb1 = *(const float4*)(xrB + tn + 4);
    const float xsA[8] = {xa0.x, xa0.y, xa0.z, xa0.w, xa1.x, xa1.y, xa1.z, xa1.w};
    const float xsB[8] = {xb0.x, xb0.y, xb0.z, xb0.w, xb1.x, xb1.y, xb1.z, xb1.w};
#pragma unroll
    for (int j = 0; j < 8; ++j) {
      // B-operands from packed h fragments
      u32x4 uA0 = {bfA[0][0], bfA[0][1], bfA[0][2], bfA[0][3]};
      u32x4 uA1 = {bfA[1][0], bfA[1][1], bfA[1][2], bfA[1][3]};
      u32x4 uA2 = {bfA[2][0], bfA[2][1], bfA[2][2], bfA[2][3]};
      u32x4 uA3 = {bfA[3][0], bfA[3][1], bfA[3][2], bfA[3][3]};
      u32x4 uB0 = {bfB[0][0], bfB[0][1], bfB[0][2], bfB[0][3]};
      u32x4 uB1 = {bfB[1][0], bfB[1][1], bfB[1][2], bfB[1][3]};
      u32x4 uB2 = {bfB[2][0], bfB[2][1], bfB[2][2], bfB[2][3]};
      u32x4 uB3 = {bfB[3][0], bfB[3][1], bfB[3][2], bfB[3][3]};
      bf16x8 BA0 = __builtin_bit_cast(bf16x8, uA0);
      bf16x8 BA1 = __builtin_bit_cast(bf16x8, uA1);
      bf16x8 BA2 = __builtin_bit_cast(bf16x8, uA2);
      bf16x8 BA3 = __builtin_bit_cast(bf16x8, uA3);
      bf16x8 BB0 = __builtin_bit_cast(bf16x8, uB0);
      bf16x8 BB1 = __builtin_bit_cast(bf16x8, uB1);
      bf16x8 BB2 = __builtin_bit_cast(bf16x8, uB2);
      bf16x8 BB3 = __builtin_bit_cast(bf16x8, uB3);

      // depth-4 k-chains, C-in = X (x-term, precomputed); A/B interleaved
      f32x16 aA0 = XA0, aA1 = XA1, aB0 = XB0, aB1 = XB1;
      aA0 = __builtin_amdgcn_mfma_f32_32x32x16_bf16(A[0][0], BA0, aA0, 0, 0, 0);
      aB0 = __builtin_amdgcn_mfma_f32_32x32x16_bf16(A[0][0], BB0, aB0, 0, 0, 0);
      aA1 = __builtin_amdgcn_mfma_f32_32x32x16_bf16(A[1][0], BA0, aA1, 0, 0, 0);
      aB1 = __builtin_amdgcn_mfma_f32_32x32x16_bf16(A[1][0], BB0, aB1, 0, 0, 0);
      aA0 = __builtin_amdgcn_mfma_f32_32x32x16_bf16(A[0][1], BA1, aA0, 0, 0, 0);
      aB0 = __builtin_amdgcn_mfma_f32_32x32x16_bf16(A[0][1], BB1, aB0, 0, 0, 0);
      aA1 = __builtin_amdgcn_mfma_f32_32x32x16_bf16(A[1][1], BA1, aA1, 0, 0, 0);
      aB1 = __builtin_amdgcn_mfma_f32_32x32x16_bf16(A[1][1], BB1, aB1, 0, 0, 0);

      // x-term MFMAs for NEXT step, issued mid-chain (off critical path)
      {
        const float xnA = (j < 7) ? xsA[j + 1] : na0.x;
        const float xnB = (j < 7) ? xsB[j + 1] : nb0.x;
        unsigned wa0, wa1, wb0, wb1;
        make_bx(xnA, sel, wa0, wa1);
        make_bx(xnB, sel, wb0, wb1);
        u32x4 ua = {wa0, wa1, 0u, 0u}, ub = {wb0, wb1, 0u, 0u};
        bf16x8 BxA = __builtin_bit_cast(bf16x8, ua);
        bf16x8 BxB = __builtin_bit_cast(bf16x8, ub);
        XA0 = __builtin_amdgcn_mfma_f32_32x32x16_bf16(Ax[0], BxA, zf, 0, 0, 0);
        XB0 = __builtin_amdgcn_mfma_f32_32x32x16_bf16(Ax[0], BxB, zf, 0, 0, 0);
        XA1 = __builtin_amdgcn_mfma_f32_32x32x16_bf16(Ax[1], BxA, zf, 0, 0, 0);
        XB1 = __builtin_amdgcn_mfma_f32_32x32x16_bf16(Ax[1], BxB, zf, 0, 0, 0);
      }

      aA0 = __builtin_amdgcn_mfma_f32_32x32x16_bf16(A[0][2], BA2, aA0, 0, 0, 0);
      aB0 = __builtin_amdgcn_mfma_f32_32x32x16_bf16(A[0][2], BB2, aB0, 0, 0, 0);
      aA1 = __builtin_amdgcn_mfma_f32_32x32x16_bf16(A[1][2], BA2, aA1, 0, 0, 0);
      aB1 = __builtin_amdgcn_mfma_f32_32x32x16_bf16(A[1][2], BB2, aB1, 0, 0, 0);
      aA0 = __builtin_amdgcn_mfma_f32_32x32x16_bf16(A[0][3], BA3, aA0, 0, 0, 0);
      aB0 = __builtin_amdgcn_mfma_f32_32x32x16_bf16(A[0][3], BB3, aB0, 0, 0, 0);
      aA1 = __builtin_amdgcn_mfma_f32_32x32x16_bf16(A[1][3], BA3, aA1, 0, 0, 0);
      aB1 = __builtin_amdgcn_mfma_f32_32x32x16_bf16(A[1][3], BB3, aB1, 0, 0, 0);

      accA0 = aA0; accA1 = aA1; accB0 = aB0; accB1 = aB1;

      // relu + pack + permlane (chain A and B interleaved)
#pragma unroll
      for (int m = 0; m < 4; ++m) {
        const int base = (m & 1) * 8;
        unsigned XA_0, XA_1, YA_0, YA_1, XB_0, XB_1, YB_0, YB_1;
        if (m < 2) {
          XA_0 = pk2_relu(aA0[base + 0], aA0[base + 1]);
          XA_1 = pk2_relu(aA0[base + 2], aA0[base + 3]);
          YA_0 = pk2_relu(aA0[base + 4], aA0[base + 5]);
          YA_1 = pk2_relu(aA0[base + 6], aA0[base + 7]);
          XB_0 = pk2_relu(aB0[base + 0], aB0[base + 1]);
          XB_1 = pk2_relu(aB0[base + 2], aB0[base + 3]);
          YB_0 = pk2_relu(aB0[base + 4], aB0[base + 5]);
          YB_1 = pk2_relu(aB0[base + 6], aB0[base + 7]);
        } else {
          XA_0 = pk2_relu(aA1[base + 0], aA1[base + 1]);
          XA_1 = pk2_relu(aA1[base + 2], aA1[base + 3]);
          YA_0 = pk2_relu(aA1[base + 4], aA1[base + 5]);
          YA_1 = pk2_relu(aA1[base + 6], aA1[base + 7]);
          XB_0 = pk2_relu(aB1[base + 0], aB1[base + 1]);
          XB_1 = pk2_relu(aB1[base + 2], aB1[base + 3]);
          YB_0 = pk2_relu(aB1[base + 4], aB1[base + 5]);
          YB_1 = pk2_relu(aB1[base + 6], aB1[base + 7]);
        }
        asm("v_permlane32_swap_b32 %0, %1" : "+v"(XA_0), "+v"(YA_0));
        asm("v_permlane32_swap_b32 %0, %1" : "+v"(XA_1), "+v"(YA_1));
        asm("v_permlane32_swap_b32 %0, %1" : "+v"(XB_0), "+v"(YB_0));
        asm("v_permlane32_swap_b32 %0, %1" : "+v"(XB_1), "+v"(YB_1));
        bfA[m][0] = XA_0; bfA[m][1] = XA_1; bfA[m][2] = YA_0; bfA[m][3] = YA_1;
        bfB[m][0] = XB_0; bfB[m][1] = XB_1; bfB[m][2] = YB_0; bfB[m][3] = YB_1;
      }
    }
    xa0 = na0; xa1 = na1; xb0 = nb0; xb1 = nb1;
  }

  // ---- epilogue: out[b] = sum_i Why[i] * relu(h_pre[i]) ----
  float pA = 0.0f, pB = 0.0f;
#pragma unroll
  for (int r = 0; r < 16; ++r) {
    const int row = (r & 3) + 8 * (r >> 2) + 4 * sel;
    const float w0 = Why[row], w1 = Why[row + 32];
    pA += w0 * fmaxf(accA0[r], 0.0f) + w1 * fmaxf(accA1[r], 0.0f);
    pB += w0 * fmaxf(accB0[r], 0.0f) + w1 * fmaxf(accB1[r], 0.0f);
  }
  pA += __shfl_xor(pA, 32, 64);
  pB += __shfl_xor(pB, 32, 64);
  if (lane < 32) {
    out[b0 + col]      = pA;
    out[b0 + 32 + col] = pB;
  }
}

extern "C" void kernel_launch(void* const* d_in, const int* in_sizes, int n_in,
                              void* d_out, int out_size, void* d_ws, size_t ws_size,
                              hipStream_t stream) {
  const float* x   = (const float*)d_in[0];
  const float* Wxh = (const float*)d_in[1];
  const float* Whh = (const float*)d_in[2];
  const float* Why = (const float*)d_in[3];
  float* out = (float*)d_out;
  (void)in_sizes; (void)n_in; (void)out_size; (void)d_ws; (void)ws_size;
  rnn_scan_kernel<<<dim3(RNN_B / 64), dim3(64), 0, stream>>>(x, Wxh, Whh, Why, out);
}

// Round 5
// 177.037 us; speedup vs baseline: 2.1814x; 2.1814x over previous
//
#include <hip/hip_runtime.h>

// RNN scan: h_{t+1} = relu(W_hh @ h_t + x_t * w_x), out = W_hy @ h_T
// B=8192, T=512, H=64.
// Model (fits rounds 1/3/4): MFMA result-blocks its wave (~60 cyc each, no
// intra-wave overlap) => T(step) ~ N_mfma*60 + N_valu*2 + fixed path.
// Round 5: halve N_mfma per wave via M-split. 2 waves per chain (block=128):
//   wave w owns C rows [32w,32w+32): 4 MFMAs (full K), packs its h-half into
//   2 frag words, exchanges via LDS (double-buffered, 1 lgkm-only barrier per
//   step -- NOT __syncthreads, whose vmcnt(0) drain would stall on the x
//   prefetch), reads all 4 frags. x-term back to v_pk_mul (round-4's x-MFMA
//   was a pessimization under the blocking model).
// Layouts (verified rounds 1-3):
//   A 32x32x16: row=lane&31, k=8*(lane>>5)+e
//   B: col=lane&31, k=8*(lane>>5)+e
//   C: col=lane&31, row=(reg&3)+8*(reg>>2)+4*(lane>>5)
//   permlane32_swap(X,Y): X'={self X|partner Y}, Y'={partner X|self Y}

typedef __bf16 bf16x8 __attribute__((ext_vector_type(8)));
typedef float f32x16 __attribute__((ext_vector_type(16)));
typedef unsigned int u32x4 __attribute__((ext_vector_type(4)));

#define RNN_B 8192
#define RNN_T 512
#define RNN_H 64

__device__ __forceinline__ unsigned pk2_relu(float a, float b) {
  float ra = fmaxf(a, 0.0f), rb = fmaxf(b, 0.0f);
  unsigned short ua = __builtin_bit_cast(unsigned short, (__bf16)ra);
  unsigned short ub = __builtin_bit_cast(unsigned short, (__bf16)rb);
  return (unsigned)ua | ((unsigned)ub << 16);
}

__global__ __launch_bounds__(128, 1) void rnn_scan_kernel(
    const float* __restrict__ x,
    const float* __restrict__ Wxh,
    const float* __restrict__ Whh,
    const float* __restrict__ Why,
    float* __restrict__ out)
{
  const int tid  = threadIdx.x;
  const int wv   = tid >> 6;      // M-half this wave owns: rows [32*wv, 32*wv+32)
  const int lane = tid & 63;
  const int col  = lane & 31;
  const int sel  = lane >> 5;
  const int b0   = blockIdx.x * 32;

  // [buf][srcwave][word][lane]: srcwave w word u holds frag m = 2*w + u
  __shared__ u32x4 xch[2][2][2][64];          // 8 KiB, 16B/lane contiguous
  __shared__ float partial[2][32];

  // ---- A fragments: this wave's 32 rows of W_hh, k-blocks m=0..3 ----
  bf16x8 A[4];
#pragma unroll
  for (int m = 0; m < 4; ++m) {
    const float* wp = Whh + (32 * wv + col) * RNN_H + 16 * m + 8 * sel;
    float4 w0 = *(const float4*)(wp);
    float4 w1 = *(const float4*)(wp + 4);
    bf16x8 f;
    f[0] = (__bf16)w0.x; f[1] = (__bf16)w0.y; f[2] = (__bf16)w0.z; f[3] = (__bf16)w0.w;
    f[4] = (__bf16)w1.x; f[5] = (__bf16)w1.y; f[6] = (__bf16)w1.z; f[7] = (__bf16)w1.w;
    A[m] = f;
  }

  // ---- w_x per accumulator slot (this wave's rows) ----
  f32x16 wxv;
#pragma unroll
  for (int r = 0; r < 16; ++r)
    wxv[r] = Wxh[32 * wv + (r & 3) + 8 * (r >> 2) + 4 * sel];

  const float* xrow = x + (size_t)(b0 + col) * RNN_T;
  float4 xc0 = *(const float4*)(xrow);
  float4 xc1 = *(const float4*)(xrow + 4);

  f32x16 zf = {};
  f32x16 acc = zf;                       // this wave's pre-relu h half
  u32x4 fr0 = {}, fr1 = {}, fr2 = {}, fr3 = {};   // B-frags m=0..3 (h_0 = 0)

  for (int tb = 0; tb < RNN_T; tb += 8) {
    const int tn = (tb + 8 < RNN_T) ? tb + 8 : tb;
    float4 xn0 = *(const float4*)(xrow + tn);
    float4 xn1 = *(const float4*)(xrow + tn + 4);
    const float xs[8] = {xc0.x, xc0.y, xc0.z, xc0.w, xc1.x, xc1.y, xc1.z, xc1.w};
#pragma unroll
    for (int j = 0; j < 8; ++j) {
      const float xv = xs[j];
      acc = wxv * xv;                    // f32-exact x-term (v_pk_mul)
      acc = __builtin_amdgcn_mfma_f32_32x32x16_bf16(A[0], __builtin_bit_cast(bf16x8, fr0), acc, 0, 0, 0);
      acc = __builtin_amdgcn_mfma_f32_32x32x16_bf16(A[1], __builtin_bit_cast(bf16x8, fr1), acc, 0, 0, 0);
      acc = __builtin_amdgcn_mfma_f32_32x32x16_bf16(A[2], __builtin_bit_cast(bf16x8, fr2), acc, 0, 0, 0);
      acc = __builtin_amdgcn_mfma_f32_32x32x16_bf16(A[3], __builtin_bit_cast(bf16x8, fr3), acc, 0, 0, 0);

      // pack own half: rows [32wv,32wv+16) -> own0 (frag m=2wv),
      //                rows [32wv+16,32wv+32) -> own1 (frag m=2wv+1)
      u32x4 own0, own1;
      {
        unsigned X0 = pk2_relu(acc[0], acc[1]);
        unsigned X1 = pk2_relu(acc[2], acc[3]);
        unsigned Y0 = pk2_relu(acc[4], acc[5]);
        unsigned Y1 = pk2_relu(acc[6], acc[7]);
        asm("v_permlane32_swap_b32 %0, %1" : "+v"(X0), "+v"(Y0));
        asm("v_permlane32_swap_b32 %0, %1" : "+v"(X1), "+v"(Y1));
        own0[0] = X0; own0[1] = X1; own0[2] = Y0; own0[3] = Y1;
      }
      {
        unsigned X0 = pk2_relu(acc[8],  acc[9]);
        unsigned X1 = pk2_relu(acc[10], acc[11]);
        unsigned Y0 = pk2_relu(acc[12], acc[13]);
        unsigned Y1 = pk2_relu(acc[14], acc[15]);
        asm("v_permlane32_swap_b32 %0, %1" : "+v"(X0), "+v"(Y0));
        asm("v_permlane32_swap_b32 %0, %1" : "+v"(X1), "+v"(Y1));
        own1[0] = X0; own1[1] = X1; own1[2] = Y0; own1[3] = Y1;
      }

      // exchange halves (double-buffered; lgkm-only drain + barrier)
      const int p = j & 1;
      xch[p][wv][0][lane] = own0;
      xch[p][wv][1][lane] = own1;
      asm volatile("s_waitcnt lgkmcnt(0)\n\ts_barrier" ::: "memory");
      fr0 = xch[p][0][0][lane];
      fr1 = xch[p][0][1][lane];
      fr2 = xch[p][1][0][lane];
      fr3 = xch[p][1][1][lane];
    }
    xc0 = xn0; xc1 = xn1;
  }

  // ---- epilogue: out[b] = sum over this wave's rows, then cross-wave ----
  float pw = 0.0f;
#pragma unroll
  for (int r = 0; r < 16; ++r) {
    const int row = 32 * wv + (r & 3) + 8 * (r >> 2) + 4 * sel;
    pw += Why[row] * fmaxf(acc[r], 0.0f);
  }
  pw += __shfl_xor(pw, 32, 64);
  if (lane < 32) partial[wv][col] = pw;
  __syncthreads();
  if (wv == 0 && lane < 32) out[b0 + col] = partial[0][col] + partial[1][col];
}

extern "C" void kernel_launch(void* const* d_in, const int* in_sizes, int n_in,
                              void* d_out, int out_size, void* d_ws, size_t ws_size,
                              hipStream_t stream) {
  const float* x   = (const float*)d_in[0];
  const float* Wxh = (const float*)d_in[1];
  const float* Whh = (const float*)d_in[2];
  const float* Why = (const float*)d_in[3];
  float* out = (float*)d_out;
  (void)in_sizes; (void)n_in; (void)out_size; (void)d_ws; (void)ws_size;
  rnn_scan_kernel<<<dim3(RNN_B / 32), dim3(128), 0, stream>>>(x, Wxh, Whh, Why, out);
}